// Round 1
// baseline (634.007 us; speedup 1.0000x reference)
//
#include <hip/hip_runtime.h>
#include <stdint.h>
#include <stddef.h>

// out[65536,1024] = X . W0^T + b0 (fp32 in/out) via bf16 MFMA.
// R3: port to the 256x256 / BK=64 / 8-wave phase-interleaved schedule
// (counted vmcnt, never drained to 0 in the main loop; granule-XOR LDS
// swizzle on both A and B; setprio around MFMA clusters; XCD-aware block
// remap). A (fp32) is reg-staged with cvt, issued 3 phases ahead of its
// ds_write; B (bf16 workspace) uses global_load_lds with pre-swizzled
// global source + swizzled ds_read.

#define BATCH   65536
#define HIDDEN  1024
#define BM      256
#define BN      256
#define BK      64
#define NT      (HIDDEN / BK)   // 16 K-tiles

typedef __bf16 bf16;
typedef __attribute__((ext_vector_type(8))) __bf16 bf16x8;
typedef __attribute__((ext_vector_type(4))) __bf16 bf16x4;
typedef __attribute__((ext_vector_type(4))) float  f32x4;

#define MEMFENCE  asm volatile("" ::: "memory")
#define WAITVM(N) asm volatile("s_waitcnt vmcnt(" #N ")" ::: "memory")
#define LGKM0     asm volatile("s_waitcnt lgkmcnt(0)" ::: "memory")
#define BARRIER() do { MEMFENCE; __builtin_amdgcn_s_barrier(); MEMFENCE; } while (0)

__device__ __forceinline__ void async_ld16(const bf16* g, bf16* l) {
    __builtin_amdgcn_global_load_lds(
        (const __attribute__((address_space(1))) uint32_t*)g,
        (__attribute__((address_space(3))) uint32_t*)l,
        16, 0, 0);
}

__device__ __forceinline__ bf16x8 cvt8(f32x4 a, f32x4 b) {
    bf16x8 r;
    r[0] = (bf16)a[0]; r[1] = (bf16)a[1]; r[2] = (bf16)a[2]; r[3] = (bf16)a[3];
    r[4] = (bf16)b[0]; r[5] = (bf16)b[1]; r[6] = (bf16)b[2]; r[7] = (bf16)b[3];
    return r;
}

__global__ void convert_w_kernel(const float* __restrict__ W, bf16* __restrict__ Wb) {
    int i = (blockIdx.x * 256 + threadIdx.x) * 4;
    f32x4 v = *(const f32x4*)(W + i);
    bf16x4 o;
    o[0] = (bf16)v[0]; o[1] = (bf16)v[1]; o[2] = (bf16)v[2]; o[3] = (bf16)v[3];
    *(bf16x4*)(Wb + i) = o;
}

// LDS byte map (dynamic, 128 KiB):
//   A: buf*32768 + row*128 + slot*16           (row 0..255, slot 0..7, bf16 granule=8 elems)
//   B: 65536 + buf*32768 + row*128 + slot*16
// Swizzle: slot = granule ^ (row & 7) on write AND read (involution).
// A half h = rows with bit6 == h  (what phases 0/2 consume, resp.)
// B half h = rows with bit5 == h  (what phases 0/1 consume, resp.)

#define READ_A(BUF, MH) do {                                                  \
    const char* _ab = smem + (BUF)*32768 + arr + (MH)*8192;                   \
    aF[0][0] = *(const bf16x8*)(_ab + 0*2048 + fsl0);                         \
    aF[0][1] = *(const bf16x8*)(_ab + 0*2048 + fsl1);                         \
    aF[1][0] = *(const bf16x8*)(_ab + 1*2048 + fsl0);                         \
    aF[1][1] = *(const bf16x8*)(_ab + 1*2048 + fsl1);                         \
    aF[2][0] = *(const bf16x8*)(_ab + 2*2048 + fsl0);                         \
    aF[2][1] = *(const bf16x8*)(_ab + 2*2048 + fsl1);                         \
    aF[3][0] = *(const bf16x8*)(_ab + 3*2048 + fsl0);                         \
    aF[3][1] = *(const bf16x8*)(_ab + 3*2048 + fsl1);                         \
} while (0)

#define READ_B(BUF, NH) do {                                                  \
    const char* _bb = smem + 65536 + (BUF)*32768 + brr + (NH)*4096;           \
    bF[NH][0][0] = *(const bf16x8*)(_bb + 0*2048 + fsl0);                     \
    bF[NH][0][1] = *(const bf16x8*)(_bb + 0*2048 + fsl1);                     \
    bF[NH][1][0] = *(const bf16x8*)(_bb + 1*2048 + fsl0);                     \
    bF[NH][1][1] = *(const bf16x8*)(_bb + 1*2048 + fsl1);                     \
} while (0)

#define MM(MH, NH, MI, NI, KS)                                                \
    acc[(MH)*4+(MI)][(NH)*2+(NI)] = __builtin_amdgcn_mfma_f32_16x16x32_bf16(  \
        aF[(MI)][(KS)], bF[(NH)][(NI)][(KS)], acc[(MH)*4+(MI)][(NH)*2+(NI)], 0, 0, 0)

#define MFMA_Q(MH, NH) do {                                                   \
    __builtin_amdgcn_s_setprio(1);                                            \
    MM(MH,NH,0,0,0); MM(MH,NH,1,0,0); MM(MH,NH,2,0,0); MM(MH,NH,3,0,0);       \
    MM(MH,NH,0,1,0); MM(MH,NH,1,1,0); MM(MH,NH,2,1,0); MM(MH,NH,3,1,0);       \
    MM(MH,NH,0,0,1); MM(MH,NH,1,0,1); MM(MH,NH,2,0,1); MM(MH,NH,3,0,1);       \
    MM(MH,NH,0,1,1); MM(MH,NH,1,1,1); MM(MH,NH,2,1,1); MM(MH,NH,3,1,1);       \
    __builtin_amdgcn_s_setprio(0);                                            \
} while (0)

// A reg-stage: 4 x dwordx4 (exactly 4 vmcnt ops -- wait counts rely on this)
#define ISSUE_LA(LR, KT, H) do {                                              \
    const f32x4* _s = (const f32x4*)(aSrc + (size_t)(H)*64*HIDDEN + (KT)*BK); \
    LR[0] = _s[0]; LR[1] = _s[1]; LR[2] = _s[2]; LR[3] = _s[3];               \
} while (0)

// B stage: 2 x global_load_lds (exactly 2 vmcnt ops)
#define ISSUE_SB(DBUF, KT, H) do {                                            \
    const bf16* _g0 = bSrc0 + (size_t)(H)*32*HIDDEN + (KT)*BK;                \
    const bf16* _g1 = bSrc1 + (size_t)(H)*32*HIDDEN + (KT)*BK;                \
    bf16* _d0 = (bf16*)(smem + 65536 + (DBUF)*32768 + (brb0 + (H)*32)*128);   \
    bf16* _d1 = (bf16*)(smem + 65536 + (DBUF)*32768 + (brb1 + (H)*32)*128);   \
    async_ld16(_g0, _d0);                                                     \
    async_ld16(_g1, _d1);                                                     \
} while (0)

#define WRITE_A(LR, DBUF, H) do {                                             \
    char* _d = smem + (DBUF)*32768 + aw_row + (H)*8192;                       \
    *(bf16x8*)(_d + aw_sl0) = cvt8(LR[0], LR[1]);                             \
    *(bf16x8*)(_d + aw_sl1) = cvt8(LR[2], LR[3]);                             \
} while (0)

// One K-tile = 4 phases. Steady-state in-flight bookkeeping (per thread):
//   ph0 issues LA0(t+1)[4] + SB0(t+1)[2]; ph1 issues LA1(t+1)[4] + SB1(t+1)[2].
//   end-ph0 WAITVM(6): SB1(t) landed   (6 = LA0+SB0 of t+1 after it)
//   end-ph3 WAITVM(6): SB0(t+1) landed (6 = LA1+SB1 of t+1 after it)
//   LA consumption waits are compiler-auto (exact counts), at WRITE_A sites.
// A1(t) ds_written in ph0 (read ph2); A0(t+1) ds_written in ph3 (read next ph0).
#define TILE_STEP(BUF, OBUF, T) do {                                          \
    /* ---- phase 0: Q(M0,N0) ---- */                                         \
    READ_A(BUF, 0); READ_B(BUF, 0);                                           \
    MEMFENCE;                                                                 \
    if ((T) < NT-1) { ISSUE_LA(la0, (T)+1, 0); }                              \
    MEMFENCE;                                                                 \
    if ((T) < NT-1) { ISSUE_SB(OBUF, (T)+1, 0); }                             \
    MEMFENCE;                                                                 \
    BARRIER();                                                                \
    MFMA_Q(0, 0);                                                             \
    WRITE_A(la1, BUF, 1);                                                     \
    if ((T) < NT-1) { WAITVM(6); } else { WAITVM(0); }                        \
    LGKM0;                                                                    \
    BARRIER();                                                                \
    /* ---- phase 1: Q(M0,N1) ---- */                                         \
    READ_B(BUF, 1);                                                           \
    MEMFENCE;                                                                 \
    if ((T) < NT-1) { ISSUE_LA(la1, (T)+1, 1); }                              \
    MEMFENCE;                                                                 \
    if ((T) < NT-1) { ISSUE_SB(OBUF, (T)+1, 1); }                             \
    MEMFENCE;                                                                 \
    BARRIER();                                                                \
    MFMA_Q(0, 1);                                                             \
    BARRIER();                                                                \
    /* ---- phase 2: Q(M1,N0) ---- */                                         \
    READ_A(BUF, 1);                                                           \
    BARRIER();                                                                \
    MFMA_Q(1, 0);                                                             \
    BARRIER();                                                                \
    /* ---- phase 3: Q(M1,N1) ---- */                                         \
    MFMA_Q(1, 1);                                                             \
    if ((T) < NT-1) { WRITE_A(la0, OBUF, 0); WAITVM(6); }                     \
    LGKM0;                                                                    \
    BARRIER();                                                                \
} while (0)

__global__ __launch_bounds__(512, 2)
void moa_gemm_kernel(const float* __restrict__ X, const bf16* __restrict__ Wb,
                     const float* __restrict__ bias, float* __restrict__ out) {
    extern __shared__ __align__(16) char smem[];

    const int tid  = threadIdx.x;
    const int wave = tid >> 6;
    const int lane = tid & 63;

    // XCD-aware remap: linear id n-fastest (m*4+n); each XCD gets a
    // contiguous 128-id chunk so the 4 blocks sharing an X row-panel and all
    // 4 B panels (2 MB, L2-resident) co-reside on one XCD. 1024 % 8 == 0.
    const int wgid  = ((blockIdx.x & 7) << 7) | (blockIdx.x >> 3);
    const int tileM = (wgid >> 2) * BM;
    const int tileN = (wgid & 3) * BN;

    const int wr = wave >> 2;   // 0..1  (M)
    const int wc = wave & 3;    // 0..3  (N)

    // ---- A staging map: thread -> (row within half, 16-elem gpair) ----
    const int ai    = tid >> 2;                       // 0..127
    const int ag    = tid & 3;                        // gpair
    const int arow0 = ((ai >> 6) << 7) + (ai & 63);   // rows with bit6==0; +h*64
    const float* aSrc = X + (size_t)(tileM + arow0) * HIDDEN + ag * 16;
    const int aw_row = arow0 * 128;                   // + h*8192
    const int aw_sl0 = ((ag * 2)     ^ (ai & 7)) * 16;
    const int aw_sl1 = ((ag * 2 + 1) ^ (ai & 7)) * 16;

    // ---- B staging map: per (half,j) chunk of 8 rows x 8 slots, linear LDS
    // dst, swizzle folded into the per-lane GLOBAL address (rule #21) ----
    const int bc0  = wave * 2;
    const int brb0 = ((bc0 >> 2) << 6) + ((bc0 & 3) << 3);
    const int brb1 = (((bc0 + 1) >> 2) << 6) + (((bc0 + 1) & 3) << 3);
    const int bg   = ((lane & 7) ^ (lane >> 3)) * 8;
    const bf16* bSrc0 = Wb + (size_t)(tileN + brb0 + (lane >> 3)) * HIDDEN + bg;
    const bf16* bSrc1 = Wb + (size_t)(tileN + brb1 + (lane >> 3)) * HIDDEN + bg;

    // ---- fragment read map (16x16x32), swizzled slots ----
    const int frow = lane & 15, fq = lane >> 4;
    const int fsl0 = ((fq)     ^ (lane & 7)) * 16;    // kstep 0
    const int fsl1 = ((4 + fq) ^ (lane & 7)) * 16;    // kstep 1
    const int arr  = (wr * 128 + frow) * 128;         // + mh*8192 + mi*2048
    const int brr  = (wc * 64  + frow) * 128;         // + nh*4096 + ni*2048

    f32x4 acc[8][4];
    #pragma unroll
    for (int i = 0; i < 8; ++i)
        #pragma unroll
        for (int j = 0; j < 4; ++j) acc[i][j] = f32x4{0.f, 0.f, 0.f, 0.f};

    bf16x8 aF[4][2];
    bf16x8 bF[2][2][2];
    f32x4  la0[4], la1[4];

    // ---- prologue: stage tile 0 into buf 0; keep SB1(0) in flight ----
    MEMFENCE;
    ISSUE_LA(la0, 0, 0);
    MEMFENCE;
    ISSUE_SB(0, 0, 0);
    MEMFENCE;
    ISSUE_LA(la1, 0, 1);
    MEMFENCE;
    ISSUE_SB(0, 0, 1);
    MEMFENCE;
    WRITE_A(la0, 0, 0);          // compiler auto-waits vmcnt for la0
    WAITVM(6);                   // SB0(0) landed (LA1+SB1 still in flight)
    LGKM0;
    BARRIER();

    #pragma unroll 1
    for (int tp = 0; tp < NT / 2; ++tp) {
        const int t0 = 2 * tp;
        const int t1 = 2 * tp + 1;
        TILE_STEP(0, 1, t0);
        TILE_STEP(1, 0, t1);
    }

    // ---- epilogue: C/D layout col=lane&15, row=(lane>>4)*4+r ----
    const int orow0 = tileM + wr * 128 + ((lane >> 4) << 2);
    const int ocol0 = tileN + wc * 64 + (lane & 15);
    const float bv0 = bias[ocol0];
    const float bv1 = bias[ocol0 + 16];
    const float bv2 = bias[ocol0 + 32];
    const float bv3 = bias[ocol0 + 48];
    #pragma unroll
    for (int mi = 0; mi < 8; ++mi) {
        #pragma unroll
        for (int r = 0; r < 4; ++r) {
            float* op = out + (size_t)(orow0 + mi * 16 + r) * HIDDEN + ocol0;
            op[0]  = acc[mi][0][r] + bv0;
            op[16] = acc[mi][1][r] + bv1;
            op[32] = acc[mi][2][r] + bv2;
            op[48] = acc[mi][3][r] + bv3;
        }
    }
}

extern "C" void kernel_launch(void* const* d_in, const int* in_sizes, int n_in,
                              void* d_out, int out_size, void* d_ws, size_t ws_size,
                              hipStream_t stream) {
    const float* x  = (const float*)d_in[0];
    const float* W  = (const float*)d_in[2];   // [8,1024,1024]; adaptor 0 first
    const float* b  = (const float*)d_in[3];   // [8,1024]
    float* out      = (float*)d_out;
    bf16*  Wb       = (bf16*)d_ws;

    // 128 KiB dynamic LDS needs the opt-in attribute (default cap is 64 KiB).
    hipFuncSetAttribute((const void*)moa_gemm_kernel,
                        hipFuncAttributeMaxDynamicSharedMemorySize, 131072);

    convert_w_kernel<<<dim3(HIDDEN * HIDDEN / (256 * 4)), dim3(256), 0, stream>>>(W, Wb);

    moa_gemm_kernel<<<dim3((BATCH / BM) * (HIDDEN / BN)), dim3(512), 131072, stream>>>(
        x, Wb, b, out);
}

// Round 2
// 582.264 us; speedup vs baseline: 1.0889x; 1.0889x over previous
//
#include <hip/hip_runtime.h>
#include <stdint.h>
#include <stddef.h>

// out[65536,1024] = X . W0^T + b0 (fp32 in/out) via bf16 MFMA.
// R4 = R3 (256x256/BK=64/8-wave phase schedule, counted vmcnt, XOR swizzle,
// setprio, XCD remap) with ONE change: coalesced A loads.
// R3's A pattern gave each global_load_dwordx4 64 one-lane 64B-line requests
// (16 rows x 4 chunks at 64B stride) -> ~4K L1 requests per K-tile per CU,
// throttling the whole vmem queue (B gl_lds retires in issue order behind A).
// R4 loads lane-contiguous (1 instr = 4 rows x 256 B = 16 full lines) and
// stages to LDS with 4x ds_write_b64 per half, same swizzled content layout.

#define BATCH   65536
#define HIDDEN  1024
#define BM      256
#define BN      256
#define BK      64
#define NT      (HIDDEN / BK)   // 16 K-tiles

typedef __bf16 bf16;
typedef __attribute__((ext_vector_type(8))) __bf16 bf16x8;
typedef __attribute__((ext_vector_type(4))) __bf16 bf16x4;
typedef __attribute__((ext_vector_type(4))) float  f32x4;

#define MEMFENCE  asm volatile("" ::: "memory")
#define WAITVM(N) asm volatile("s_waitcnt vmcnt(" #N ")" ::: "memory")
#define LGKM0     asm volatile("s_waitcnt lgkmcnt(0)" ::: "memory")
#define BARRIER() do { MEMFENCE; __builtin_amdgcn_s_barrier(); MEMFENCE; } while (0)

__device__ __forceinline__ void async_ld16(const bf16* g, bf16* l) {
    __builtin_amdgcn_global_load_lds(
        (const __attribute__((address_space(1))) uint32_t*)g,
        (__attribute__((address_space(3))) uint32_t*)l,
        16, 0, 0);
}

__device__ __forceinline__ bf16x4 cvt4(f32x4 a) {
    bf16x4 r;
    r[0] = (bf16)a[0]; r[1] = (bf16)a[1]; r[2] = (bf16)a[2]; r[3] = (bf16)a[3];
    return r;
}

__global__ void convert_w_kernel(const float* __restrict__ W, bf16* __restrict__ Wb) {
    int i = (blockIdx.x * 256 + threadIdx.x) * 4;
    f32x4 v = *(const f32x4*)(W + i);
    bf16x4 o;
    o[0] = (bf16)v[0]; o[1] = (bf16)v[1]; o[2] = (bf16)v[2]; o[3] = (bf16)v[3];
    *(bf16x4*)(Wb + i) = o;
}

// LDS byte map (dynamic, 128 KiB):
//   A: buf*32768 + row*128 + slot*16           (row 0..255, slot 0..7)
//   B: 65536 + buf*32768 + row*128 + slot*16
// Swizzle: slot = linear_slot ^ (row & 7) on write AND read (involution).
// A half h = rows with bit6 == h; B half h = rows with bit5 == h.

#define READ_A(BUF, MH) do {                                                  \
    const char* _ab = smem + (BUF)*32768 + arr + (MH)*8192;                   \
    aF[0][0] = *(const bf16x8*)(_ab + 0*2048 + fsl0);                         \
    aF[0][1] = *(const bf16x8*)(_ab + 0*2048 + fsl1);                         \
    aF[1][0] = *(const bf16x8*)(_ab + 1*2048 + fsl0);                         \
    aF[1][1] = *(const bf16x8*)(_ab + 1*2048 + fsl1);                         \
    aF[2][0] = *(const bf16x8*)(_ab + 2*2048 + fsl0);                         \
    aF[2][1] = *(const bf16x8*)(_ab + 2*2048 + fsl1);                         \
    aF[3][0] = *(const bf16x8*)(_ab + 3*2048 + fsl0);                         \
    aF[3][1] = *(const bf16x8*)(_ab + 3*2048 + fsl1);                         \
} while (0)

#define READ_B(BUF, NH) do {                                                  \
    const char* _bb = smem + 65536 + (BUF)*32768 + brr + (NH)*4096;           \
    bF[NH][0][0] = *(const bf16x8*)(_bb + 0*2048 + fsl0);                     \
    bF[NH][0][1] = *(const bf16x8*)(_bb + 0*2048 + fsl1);                     \
    bF[NH][1][0] = *(const bf16x8*)(_bb + 1*2048 + fsl0);                     \
    bF[NH][1][1] = *(const bf16x8*)(_bb + 1*2048 + fsl1);                     \
} while (0)

#define MM(MH, NH, MI, NI, KS)                                                \
    acc[(MH)*4+(MI)][(NH)*2+(NI)] = __builtin_amdgcn_mfma_f32_16x16x32_bf16(  \
        aF[(MI)][(KS)], bF[(NH)][(NI)][(KS)], acc[(MH)*4+(MI)][(NH)*2+(NI)], 0, 0, 0)

#define MFMA_Q(MH, NH) do {                                                   \
    __builtin_amdgcn_s_setprio(1);                                            \
    MM(MH,NH,0,0,0); MM(MH,NH,1,0,0); MM(MH,NH,2,0,0); MM(MH,NH,3,0,0);       \
    MM(MH,NH,0,1,0); MM(MH,NH,1,1,0); MM(MH,NH,2,1,0); MM(MH,NH,3,1,0);       \
    MM(MH,NH,0,0,1); MM(MH,NH,1,0,1); MM(MH,NH,2,0,1); MM(MH,NH,3,0,1);       \
    MM(MH,NH,0,1,1); MM(MH,NH,1,1,1); MM(MH,NH,2,1,1); MM(MH,NH,3,1,1);       \
    __builtin_amdgcn_s_setprio(0);                                            \
} while (0)

// A reg-stage: 4 x dwordx4, LANE-CONTIGUOUS (exactly 4 vmcnt ops).
// Instr i: rows (tid>>4) + H*64 + {0,32,128,160}, bytes (tid&15)*16 of the
// row's 256-B K-slice -> per wave-instr 4 rows x 256 B contiguous.
// Row offsets are all 0 mod 8, and bit6 of every row == H (half invariant).
#define ISSUE_LA(LR, KT, H) do {                                              \
    const float* _s = aSrc + (size_t)(H)*64*HIDDEN + (KT)*BK;                 \
    LR[0] = *(const f32x4*)(_s);                                              \
    LR[1] = *(const f32x4*)(_s +  32*HIDDEN);                                 \
    LR[2] = *(const f32x4*)(_s + 128*HIDDEN);                                 \
    LR[3] = *(const f32x4*)(_s + 160*HIDDEN);                                 \
} while (0)

// B stage: 2 x global_load_lds (exactly 2 vmcnt ops)
#define ISSUE_SB(DBUF, KT, H) do {                                            \
    const bf16* _g0 = bSrc0 + (size_t)(H)*32*HIDDEN + (KT)*BK;                \
    const bf16* _g1 = bSrc1 + (size_t)(H)*32*HIDDEN + (KT)*BK;                \
    bf16* _d0 = (bf16*)(smem + 65536 + (DBUF)*32768 + (brb0 + (H)*32)*128);   \
    bf16* _d1 = (bf16*)(smem + 65536 + (DBUF)*32768 + (brb1 + (H)*32)*128);   \
    async_ld16(_g0, _d0);                                                     \
    async_ld16(_g1, _d1);                                                     \
} while (0)

// 4 x ds_write_b64; same swizzled content layout as the b128 reads expect.
// (row&7) is identical for all 4 rows (offsets 0 mod 8) -> one swizzle calc.
#define WRITE_A(LR, DBUF, H) do {                                             \
    char* _d = smem + (DBUF)*32768 + aw_byte + (H)*8192;                      \
    *(bf16x4*)(_d +     0) = cvt4(LR[0]);                                     \
    *(bf16x4*)(_d +  4096) = cvt4(LR[1]);                                     \
    *(bf16x4*)(_d + 16384) = cvt4(LR[2]);                                     \
    *(bf16x4*)(_d + 20480) = cvt4(LR[3]);                                     \
} while (0)

// One K-tile = 4 phases. Steady-state in-flight bookkeeping (per thread):
//   ph0 issues LA0(t+1)[4] + SB0(t+1)[2]; ph1 issues LA1(t+1)[4] + SB1(t+1)[2].
//   end-ph0 WAITVM(6): SB1(t) landed   (6 = LA0+SB0 of t+1 after it)
//   end-ph3 WAITVM(6): SB0(t+1) landed (6 = LA1+SB1 of t+1 after it)
//   LA consumption waits are compiler-auto (exact counts), at WRITE_A sites.
// A1(t) ds_written in ph0 (read ph2); A0(t+1) ds_written in ph3 (read next ph0).
#define TILE_STEP(BUF, OBUF, T) do {                                          \
    /* ---- phase 0: Q(M0,N0) ---- */                                         \
    READ_A(BUF, 0); READ_B(BUF, 0);                                           \
    MEMFENCE;                                                                 \
    if ((T) < NT-1) { ISSUE_LA(la0, (T)+1, 0); }                              \
    MEMFENCE;                                                                 \
    if ((T) < NT-1) { ISSUE_SB(OBUF, (T)+1, 0); }                             \
    MEMFENCE;                                                                 \
    BARRIER();                                                                \
    MFMA_Q(0, 0);                                                             \
    WRITE_A(la1, BUF, 1);                                                     \
    if ((T) < NT-1) { WAITVM(6); } else { WAITVM(0); }                        \
    LGKM0;                                                                    \
    BARRIER();                                                                \
    /* ---- phase 1: Q(M0,N1) ---- */                                         \
    READ_B(BUF, 1);                                                           \
    MEMFENCE;                                                                 \
    if ((T) < NT-1) { ISSUE_LA(la1, (T)+1, 1); }                              \
    MEMFENCE;                                                                 \
    if ((T) < NT-1) { ISSUE_SB(OBUF, (T)+1, 1); }                             \
    MEMFENCE;                                                                 \
    BARRIER();                                                                \
    MFMA_Q(0, 1);                                                             \
    BARRIER();                                                                \
    /* ---- phase 2: Q(M1,N0) ---- */                                         \
    READ_A(BUF, 1);                                                           \
    BARRIER();                                                                \
    MFMA_Q(1, 0);                                                             \
    BARRIER();                                                                \
    /* ---- phase 3: Q(M1,N1) ---- */                                         \
    MFMA_Q(1, 1);                                                             \
    if ((T) < NT-1) { WRITE_A(la0, OBUF, 0); WAITVM(6); }                     \
    LGKM0;                                                                    \
    BARRIER();                                                                \
} while (0)

__global__ __launch_bounds__(512, 2)
void moa_gemm_kernel(const float* __restrict__ X, const bf16* __restrict__ Wb,
                     const float* __restrict__ bias, float* __restrict__ out) {
    extern __shared__ __align__(16) char smem[];

    const int tid  = threadIdx.x;
    const int wave = tid >> 6;
    const int lane = tid & 63;

    // XCD-aware remap: each XCD gets a contiguous 128-id chunk; the 4 blocks
    // sharing an X row-panel and all 4 B panels (2 MB, L2-resident) co-reside
    // on one XCD. 1024 % 8 == 0.
    const int wgid  = ((blockIdx.x & 7) << 7) | (blockIdx.x >> 3);
    const int tileM = (wgid >> 2) * BM;
    const int tileN = (wgid & 3) * BN;

    const int wr = wave >> 2;   // 0..1  (M)
    const int wc = wave & 3;    // 0..3  (N)

    // ---- A staging map (coalesced): lane-contiguous loads ----
    const float* aSrc = X + (size_t)(tileM + (tid >> 4)) * HIDDEN + (tid & 15) * 4;
    // LDS write base: row (tid>>4), 8B half-slot h=(tid&15): slot=h>>1, sub=h&1
    const int aw_byte = (tid >> 4) * 128
                      + ((((tid & 15) >> 1) ^ ((tid >> 4) & 7)) * 16)
                      + (tid & 1) * 8;

    // ---- B staging map: per (half,j) chunk of 8 rows x 8 slots, linear LDS
    // dst, swizzle folded into the per-lane GLOBAL address ----
    const int bc0  = wave * 2;
    const int brb0 = ((bc0 >> 2) << 6) + ((bc0 & 3) << 3);
    const int brb1 = (((bc0 + 1) >> 2) << 6) + (((bc0 + 1) & 3) << 3);
    const int bg   = ((lane & 7) ^ (lane >> 3)) * 8;
    const bf16* bSrc0 = Wb + (size_t)(tileN + brb0 + (lane >> 3)) * HIDDEN + bg;
    const bf16* bSrc1 = Wb + (size_t)(tileN + brb1 + (lane >> 3)) * HIDDEN + bg;

    // ---- fragment read map (16x16x32), swizzled slots ----
    const int frow = lane & 15, fq = lane >> 4;
    const int fsl0 = ((fq)     ^ (lane & 7)) * 16;    // kstep 0
    const int fsl1 = ((4 + fq) ^ (lane & 7)) * 16;    // kstep 1
    const int arr  = (wr * 128 + frow) * 128;         // + mh*8192 + mi*2048
    const int brr  = (wc * 64  + frow) * 128;         // + nh*4096 + ni*2048

    f32x4 acc[8][4];
    #pragma unroll
    for (int i = 0; i < 8; ++i)
        #pragma unroll
        for (int j = 0; j < 4; ++j) acc[i][j] = f32x4{0.f, 0.f, 0.f, 0.f};

    bf16x8 aF[4][2];
    bf16x8 bF[2][2][2];
    f32x4  la0[4], la1[4];

    // ---- prologue: stage tile 0 into buf 0; keep SB1(0)+LA1(0) in flight ----
    MEMFENCE;
    ISSUE_LA(la0, 0, 0);
    MEMFENCE;
    ISSUE_SB(0, 0, 0);
    MEMFENCE;
    ISSUE_LA(la1, 0, 1);
    MEMFENCE;
    ISSUE_SB(0, 0, 1);
    MEMFENCE;
    WRITE_A(la0, 0, 0);          // compiler auto-waits vmcnt for la0
    WAITVM(6);                   // SB0(0) landed (LA1+SB1 still in flight)
    LGKM0;
    BARRIER();

    #pragma unroll 1
    for (int tp = 0; tp < NT / 2; ++tp) {
        const int t0 = 2 * tp;
        const int t1 = 2 * tp + 1;
        TILE_STEP(0, 1, t0);
        TILE_STEP(1, 0, t1);
    }

    // ---- epilogue: C/D layout col=lane&15, row=(lane>>4)*4+r ----
    const int orow0 = tileM + wr * 128 + ((lane >> 4) << 2);
    const int ocol0 = tileN + wc * 64 + (lane & 15);
    const float bv0 = bias[ocol0];
    const float bv1 = bias[ocol0 + 16];
    const float bv2 = bias[ocol0 + 32];
    const float bv3 = bias[ocol0 + 48];
    #pragma unroll
    for (int mi = 0; mi < 8; ++mi) {
        #pragma unroll
        for (int r = 0; r < 4; ++r) {
            float* op = out + (size_t)(orow0 + mi * 16 + r) * HIDDEN + ocol0;
            op[0]  = acc[mi][0][r] + bv0;
            op[16] = acc[mi][1][r] + bv1;
            op[32] = acc[mi][2][r] + bv2;
            op[48] = acc[mi][3][r] + bv3;
        }
    }
}

extern "C" void kernel_launch(void* const* d_in, const int* in_sizes, int n_in,
                              void* d_out, int out_size, void* d_ws, size_t ws_size,
                              hipStream_t stream) {
    const float* x  = (const float*)d_in[0];
    const float* W  = (const float*)d_in[2];   // [8,1024,1024]; adaptor 0 first
    const float* b  = (const float*)d_in[3];   // [8,1024]
    float* out      = (float*)d_out;
    bf16*  Wb       = (bf16*)d_ws;

    // 128 KiB dynamic LDS needs the opt-in attribute (default cap is 64 KiB).
    hipFuncSetAttribute((const void*)moa_gemm_kernel,
                        hipFuncAttributeMaxDynamicSharedMemorySize, 131072);

    convert_w_kernel<<<dim3(HIDDEN * HIDDEN / (256 * 4)), dim3(256), 0, stream>>>(W, Wb);

    moa_gemm_kernel<<<dim3((BATCH / BM) * (HIDDEN / BN)), dim3(512), 131072, stream>>>(
        x, Wb, b, out);
}

// Round 3
// 565.489 us; speedup vs baseline: 1.1212x; 1.0297x over previous
//
#include <hip/hip_runtime.h>
#include <stdint.h>
#include <stddef.h>

// out[65536,1024] = X . W0^T + b0 (fp32 in/out) via bf16 MFMA.
// R5 = R4 (256x256/BK=64/8-wave phase schedule, coalesced reg-staged A,
// XOR swizzle, setprio, XCD remap) with ONE change: B prefetch distance
// 3 -> 7-8 phases. SB(t+2) is issued in ph3 of tile t into buf[t&1] (whose
// reads all completed by end-ph2), replacing the per-tile end-ph0 WAITVM(6)
// with a single end-ph3 WAITVM(12). Rationale: counters show both pipes
// issue only their static work (MfmaUtil 21.5% ~= floor) and ~6.5K cyc/tile
// is pure wait -> block-wide convoy on exposed ~1K-cyc global-load latency
// (sibling blocks MSHR-merge on the same X lines, so reuse saves BW not
// latency). 3-phase slack was not enough; 7-8 phases is.

#define BATCH   65536
#define HIDDEN  1024
#define BM      256
#define BN      256
#define BK      64
#define NT      (HIDDEN / BK)   // 16 K-tiles

typedef __bf16 bf16;
typedef __attribute__((ext_vector_type(8))) __bf16 bf16x8;
typedef __attribute__((ext_vector_type(4))) __bf16 bf16x4;
typedef __attribute__((ext_vector_type(4))) float  f32x4;

#define MEMFENCE  asm volatile("" ::: "memory")
#define WAITVM(N) asm volatile("s_waitcnt vmcnt(" #N ")" ::: "memory")
#define LGKM0     asm volatile("s_waitcnt lgkmcnt(0)" ::: "memory")
#define BARRIER() do { MEMFENCE; __builtin_amdgcn_s_barrier(); MEMFENCE; } while (0)

__device__ __forceinline__ void async_ld16(const bf16* g, bf16* l) {
    __builtin_amdgcn_global_load_lds(
        (const __attribute__((address_space(1))) uint32_t*)g,
        (__attribute__((address_space(3))) uint32_t*)l,
        16, 0, 0);
}

__device__ __forceinline__ bf16x4 cvt4(f32x4 a) {
    bf16x4 r;
    r[0] = (bf16)a[0]; r[1] = (bf16)a[1]; r[2] = (bf16)a[2]; r[3] = (bf16)a[3];
    return r;
}

__global__ void convert_w_kernel(const float* __restrict__ W, bf16* __restrict__ Wb) {
    int i = (blockIdx.x * 256 + threadIdx.x) * 4;
    f32x4 v = *(const f32x4*)(W + i);
    bf16x4 o;
    o[0] = (bf16)v[0]; o[1] = (bf16)v[1]; o[2] = (bf16)v[2]; o[3] = (bf16)v[3];
    *(bf16x4*)(Wb + i) = o;
}

// LDS byte map (dynamic, 128 KiB):
//   A: buf*32768 + row*128 + slot*16           (row 0..255, slot 0..7)
//   B: 65536 + buf*32768 + row*128 + slot*16
// Swizzle: slot = linear_slot ^ (row & 7) on write AND read (involution).
// A half h = rows with bit6 == h; B half h = rows with bit5 == h.

#define READ_A(BUF, MH) do {                                                  \
    const char* _ab = smem + (BUF)*32768 + arr + (MH)*8192;                   \
    aF[0][0] = *(const bf16x8*)(_ab + 0*2048 + fsl0);                         \
    aF[0][1] = *(const bf16x8*)(_ab + 0*2048 + fsl1);                         \
    aF[1][0] = *(const bf16x8*)(_ab + 1*2048 + fsl0);                         \
    aF[1][1] = *(const bf16x8*)(_ab + 1*2048 + fsl1);                         \
    aF[2][0] = *(const bf16x8*)(_ab + 2*2048 + fsl0);                         \
    aF[2][1] = *(const bf16x8*)(_ab + 2*2048 + fsl1);                         \
    aF[3][0] = *(const bf16x8*)(_ab + 3*2048 + fsl0);                         \
    aF[3][1] = *(const bf16x8*)(_ab + 3*2048 + fsl1);                         \
} while (0)

#define READ_B(BUF, NH) do {                                                  \
    const char* _bb = smem + 65536 + (BUF)*32768 + brr + (NH)*4096;           \
    bF[NH][0][0] = *(const bf16x8*)(_bb + 0*2048 + fsl0);                     \
    bF[NH][0][1] = *(const bf16x8*)(_bb + 0*2048 + fsl1);                     \
    bF[NH][1][0] = *(const bf16x8*)(_bb + 1*2048 + fsl0);                     \
    bF[NH][1][1] = *(const bf16x8*)(_bb + 1*2048 + fsl1);                     \
} while (0)

#define MM(MH, NH, MI, NI, KS)                                                \
    acc[(MH)*4+(MI)][(NH)*2+(NI)] = __builtin_amdgcn_mfma_f32_16x16x32_bf16(  \
        aF[(MI)][(KS)], bF[(NH)][(NI)][(KS)], acc[(MH)*4+(MI)][(NH)*2+(NI)], 0, 0, 0)

#define MFMA_Q(MH, NH) do {                                                   \
    __builtin_amdgcn_s_setprio(1);                                            \
    MM(MH,NH,0,0,0); MM(MH,NH,1,0,0); MM(MH,NH,2,0,0); MM(MH,NH,3,0,0);       \
    MM(MH,NH,0,1,0); MM(MH,NH,1,1,0); MM(MH,NH,2,1,0); MM(MH,NH,3,1,0);       \
    MM(MH,NH,0,0,1); MM(MH,NH,1,0,1); MM(MH,NH,2,0,1); MM(MH,NH,3,0,1);       \
    MM(MH,NH,0,1,1); MM(MH,NH,1,1,1); MM(MH,NH,2,1,1); MM(MH,NH,3,1,1);       \
    __builtin_amdgcn_s_setprio(0);                                            \
} while (0)

// A reg-stage: 4 x dwordx4, LANE-CONTIGUOUS (exactly 4 vmcnt ops).
// Instr i: rows (tid>>4) + H*64 + {0,32,128,160}, bytes (tid&15)*16 of the
// row's 256-B K-slice -> per wave-instr 4 rows x 256 B contiguous.
#define ISSUE_LA(LR, KT, H) do {                                              \
    const float* _s = aSrc + (size_t)(H)*64*HIDDEN + (KT)*BK;                 \
    LR[0] = *(const f32x4*)(_s);                                              \
    LR[1] = *(const f32x4*)(_s +  32*HIDDEN);                                 \
    LR[2] = *(const f32x4*)(_s + 128*HIDDEN);                                 \
    LR[3] = *(const f32x4*)(_s + 160*HIDDEN);                                 \
} while (0)

// B stage: 2 x global_load_lds per half (exactly 2 vmcnt ops)
#define ISSUE_SB(DBUF, KT, H) do {                                            \
    const bf16* _g0 = bSrc0 + (size_t)(H)*32*HIDDEN + (KT)*BK;                \
    const bf16* _g1 = bSrc1 + (size_t)(H)*32*HIDDEN + (KT)*BK;                \
    bf16* _d0 = (bf16*)(smem + 65536 + (DBUF)*32768 + (brb0 + (H)*32)*128);   \
    bf16* _d1 = (bf16*)(smem + 65536 + (DBUF)*32768 + (brb1 + (H)*32)*128);   \
    async_ld16(_g0, _d0);                                                     \
    async_ld16(_g1, _d1);                                                     \
} while (0)

// 4 x ds_write_b64; same swizzled content layout as the b128 reads expect.
#define WRITE_A(LR, DBUF, H) do {                                             \
    char* _d = smem + (DBUF)*32768 + aw_byte + (H)*8192;                      \
    *(bf16x4*)(_d +     0) = cvt4(LR[0]);                                     \
    *(bf16x4*)(_d +  4096) = cvt4(LR[1]);                                     \
    *(bf16x4*)(_d + 16384) = cvt4(LR[2]);                                     \
    *(bf16x4*)(_d + 20480) = cvt4(LR[3]);                                     \
} while (0)

// One K-tile = 4 phases. In-flight bookkeeping (per thread), steady state:
//   ph0 issues LA0(t+1)[4]; ph1 issues LA1(t+1)[4]; ph3 issues SB(t+2)[4]
//   (into buf[t&1], whose reads all completed by end-ph2 of t).
//   end-ph3(t) WAITVM(12): SB(t+1) landed (after it: LA0[4]+LA1[4]+SB(t+2)[4]).
//   B slack = 7-8 phases; LA consumption auto-waits at WRITE_A (3-phase slack).
#define TILE_STEP(BUF, OBUF, T) do {                                          \
    /* ---- phase 0: Q(M0,N0) ---- */                                         \
    READ_A(BUF, 0); READ_B(BUF, 0);                                           \
    MEMFENCE;                                                                 \
    if ((T) < NT-1) { ISSUE_LA(la0, (T)+1, 0); }                              \
    MEMFENCE;                                                                 \
    BARRIER();                                                                \
    MFMA_Q(0, 0);                                                             \
    WRITE_A(la1, BUF, 1);                                                     \
    LGKM0;                                                                    \
    BARRIER();                                                                \
    /* ---- phase 1: Q(M0,N1) ---- */                                         \
    READ_B(BUF, 1);                                                           \
    MEMFENCE;                                                                 \
    if ((T) < NT-1) { ISSUE_LA(la1, (T)+1, 1); }                              \
    MEMFENCE;                                                                 \
    BARRIER();                                                                \
    MFMA_Q(0, 1);                                                             \
    BARRIER();                                                                \
    /* ---- phase 2: Q(M1,N0) ---- */                                         \
    READ_A(BUF, 1);                                                           \
    BARRIER();                                                                \
    MFMA_Q(1, 0);                                                             \
    BARRIER();                                                                \
    /* ---- phase 3: Q(M1,N1) ---- */                                         \
    MFMA_Q(1, 1);                                                             \
    MEMFENCE;                                                                 \
    if ((T) + 2 < NT) { ISSUE_SB(BUF, (T)+2, 0); ISSUE_SB(BUF, (T)+2, 1); }   \
    MEMFENCE;                                                                 \
    if ((T) < NT-1) { WRITE_A(la0, OBUF, 0); }                                \
    if ((T) + 2 < NT)      { WAITVM(12); }                                    \
    else if ((T) + 1 < NT) { WAITVM(8); }                                     \
    LGKM0;                                                                    \
    BARRIER();                                                                \
} while (0)

__global__ __launch_bounds__(512, 2)
void moa_gemm_kernel(const float* __restrict__ X, const bf16* __restrict__ Wb,
                     const float* __restrict__ bias, float* __restrict__ out) {
    extern __shared__ __align__(16) char smem[];

    const int tid  = threadIdx.x;
    const int wave = tid >> 6;
    const int lane = tid & 63;

    // XCD-aware remap: each XCD gets a contiguous 128-id chunk; the 4 blocks
    // sharing an X row-panel and all 4 B panels co-reside on one XCD.
    const int wgid  = ((blockIdx.x & 7) << 7) | (blockIdx.x >> 3);
    const int tileM = (wgid >> 2) * BM;
    const int tileN = (wgid & 3) * BN;

    const int wr = wave >> 2;   // 0..1  (M)
    const int wc = wave & 3;    // 0..3  (N)

    // ---- A staging map (coalesced): lane-contiguous loads ----
    const float* aSrc = X + (size_t)(tileM + (tid >> 4)) * HIDDEN + (tid & 15) * 4;
    const int aw_byte = (tid >> 4) * 128
                      + ((((tid & 15) >> 1) ^ ((tid >> 4) & 7)) * 16)
                      + (tid & 1) * 8;

    // ---- B staging map: per (half,j) chunk of 8 rows x 8 slots, linear LDS
    // dst, swizzle folded into the per-lane GLOBAL address ----
    const int bc0  = wave * 2;
    const int brb0 = ((bc0 >> 2) << 6) + ((bc0 & 3) << 3);
    const int brb1 = (((bc0 + 1) >> 2) << 6) + (((bc0 + 1) & 3) << 3);
    const int bg   = ((lane & 7) ^ (lane >> 3)) * 8;
    const bf16* bSrc0 = Wb + (size_t)(tileN + brb0 + (lane >> 3)) * HIDDEN + bg;
    const bf16* bSrc1 = Wb + (size_t)(tileN + brb1 + (lane >> 3)) * HIDDEN + bg;

    // ---- fragment read map (16x16x32), swizzled slots ----
    const int frow = lane & 15, fq = lane >> 4;
    const int fsl0 = ((fq)     ^ (lane & 7)) * 16;    // kstep 0
    const int fsl1 = ((4 + fq) ^ (lane & 7)) * 16;    // kstep 1
    const int arr  = (wr * 128 + frow) * 128;         // + mh*8192 + mi*2048
    const int brr  = (wc * 64  + frow) * 128;         // + nh*4096 + ni*2048

    f32x4 acc[8][4];
    #pragma unroll
    for (int i = 0; i < 8; ++i)
        #pragma unroll
        for (int j = 0; j < 4; ++j) acc[i][j] = f32x4{0.f, 0.f, 0.f, 0.f};

    bf16x8 aF[4][2];
    bf16x8 bF[2][2][2];
    f32x4  la0[4], la1[4];

    // ---- prologue: A(0) both halves -> regs -> buf0; SB(0)->buf0 and
    // SB(1)->buf1 issued up front (B runs 2 tiles ahead from the start) ----
    MEMFENCE;
    ISSUE_LA(la0, 0, 0);
    MEMFENCE;
    ISSUE_LA(la1, 0, 1);
    MEMFENCE;
    ISSUE_SB(0, 0, 0);
    ISSUE_SB(0, 0, 1);
    MEMFENCE;
    ISSUE_SB(1, 1, 0);
    ISSUE_SB(1, 1, 1);
    MEMFENCE;
    WRITE_A(la0, 0, 0);          // auto-waits vmcnt for la0
    WRITE_A(la1, 0, 1);          // auto-waits vmcnt for la1
    WAITVM(4);                   // SB(0) landed (SB(1)'s 4 still in flight)
    LGKM0;
    BARRIER();

    #pragma unroll 1
    for (int tp = 0; tp < NT / 2; ++tp) {
        const int t0 = 2 * tp;
        const int t1 = 2 * tp + 1;
        TILE_STEP(0, 1, t0);
        TILE_STEP(1, 0, t1);
    }

    // ---- epilogue: C/D layout col=lane&15, row=(lane>>4)*4+r ----
    const int orow0 = tileM + wr * 128 + ((lane >> 4) << 2);
    const int ocol0 = tileN + wc * 64 + (lane & 15);
    const float bv0 = bias[ocol0];
    const float bv1 = bias[ocol0 + 16];
    const float bv2 = bias[ocol0 + 32];
    const float bv3 = bias[ocol0 + 48];
    #pragma unroll
    for (int mi = 0; mi < 8; ++mi) {
        #pragma unroll
        for (int r = 0; r < 4; ++r) {
            float* op = out + (size_t)(orow0 + mi * 16 + r) * HIDDEN + ocol0;
            op[0]  = acc[mi][0][r] + bv0;
            op[16] = acc[mi][1][r] + bv1;
            op[32] = acc[mi][2][r] + bv2;
            op[48] = acc[mi][3][r] + bv3;
        }
    }
}

extern "C" void kernel_launch(void* const* d_in, const int* in_sizes, int n_in,
                              void* d_out, int out_size, void* d_ws, size_t ws_size,
                              hipStream_t stream) {
    const float* x  = (const float*)d_in[0];
    const float* W  = (const float*)d_in[2];   // [8,1024,1024]; adaptor 0 first
    const float* b  = (const float*)d_in[3];   // [8,1024]
    float* out      = (float*)d_out;
    bf16*  Wb       = (bf16*)d_ws;

    hipFuncSetAttribute((const void*)moa_gemm_kernel,
                        hipFuncAttributeMaxDynamicSharedMemorySize, 131072);

    convert_w_kernel<<<dim3(HIDDEN * HIDDEN / (256 * 4)), dim3(256), 0, stream>>>(W, Wb);

    moa_gemm_kernel<<<dim3((BATCH / BM) * (HIDDEN / BN)), dim3(512), 131072, stream>>>(
        x, Wb, b, out);
}